// Round 1
// baseline (4380.450 us; speedup 1.0000x reference)
//
#include <hip/hip_runtime.h>

#define NN 20000
#define NE 640000
#define NF 128
#define EF 32
#define HD 128
#define NL 3

constexpr int TILE_E = 16;
constexpr int TILE_N = 16;
constexpr int PADE = 20; // padded row stride (floats) for transposed LDS tiles

// ---------------- node embedding: h = coords @ W_node + b_node ----------------
__global__ __launch_bounds__(128) void k_node_embed(
    const float* __restrict__ coords, const float* __restrict__ Wn,
    const float* __restrict__ bn, float* __restrict__ h)
{
    const int node = blockIdx.x;
    const int f = threadIdx.x;
    __shared__ float c[8];
    if (f < 6) c[f] = coords[node * 6 + f];
    __syncthreads();
    float acc = bn[f];
#pragma unroll
    for (int k = 0; k < 6; ++k) acc = fmaf(c[k], Wn[k * NF + f], acc);
    h[(size_t)node * NF + f] = acc;
}

// ---------------- fused edge message + scatter-add ----------------
// m = relu([h[src],h[dst],e] @ W1 + b1) @ W2 + b2 ; agg[dst] += m
// e computed on the fly from edge_distances @ W_edge + b_edge.
__global__ __launch_bounds__(256) void k_message(
    const float* __restrict__ h, const int* __restrict__ ei,
    const float* __restrict__ dist,
    const float* __restrict__ We, const float* __restrict__ be,
    const float* __restrict__ W1, const float* __restrict__ b1,
    const float* __restrict__ W2, const float* __restrict__ b2,
    float* __restrict__ agg)
{
    __shared__ float sA[2 * NF + EF][PADE]; // m_in transposed: [k][edge]
    __shared__ float sT[HD][PADE];          // t transposed: [k][edge]
    __shared__ int s_src[TILE_E], s_dst[TILE_E];

    const int tid = threadIdx.x;
    const int e0 = blockIdx.x * TILE_E;
    if (tid < TILE_E) {
        s_src[tid] = ei[e0 + tid];
        s_dst[tid] = ei[NE + e0 + tid];
    }
    __syncthreads();

    // gather phase: fill sA[k][i] for k in [0,288), i in [0,16)
    for (int idx = tid; idx < TILE_E * (2 * NF + EF); idx += 256) {
        const int i = idx / (2 * NF + EF);
        const int k = idx - i * (2 * NF + EF);
        float v;
        if (k < NF) {
            v = h[(size_t)s_src[i] * NF + k];
        } else if (k < 2 * NF) {
            v = h[(size_t)s_dst[i] * NF + (k - NF)];
        } else {
            const int j = k - 2 * NF;
            float a = be[j];
            const float* dr = dist + (size_t)(e0 + i) * EF;
#pragma unroll
            for (int q = 0; q < EF; ++q) a = fmaf(dr[q], We[q * EF + j], a);
            v = a;
        }
        sA[k][i] = v;
    }
    __syncthreads();

    const int f = tid & (HD - 1);
    const int eh = tid >> 7; // 0 or 1 -> edges [eh*8, eh*8+8)

    // GEMM1: t[i][f] = relu(b1[f] + sum_k sA[k][i] * W1[k][f])
    float acc[8];
    {
        const float bb = b1[f];
#pragma unroll
        for (int r = 0; r < 8; ++r) acc[r] = bb;
    }
    for (int k = 0; k < 2 * NF + EF; ++k) {
        const float w = W1[k * HD + f];
        const float4* ap = reinterpret_cast<const float4*>(&sA[k][eh * 8]);
        const float4 a0 = ap[0], a1 = ap[1];
        acc[0] = fmaf(a0.x, w, acc[0]);
        acc[1] = fmaf(a0.y, w, acc[1]);
        acc[2] = fmaf(a0.z, w, acc[2]);
        acc[3] = fmaf(a0.w, w, acc[3]);
        acc[4] = fmaf(a1.x, w, acc[4]);
        acc[5] = fmaf(a1.y, w, acc[5]);
        acc[6] = fmaf(a1.z, w, acc[6]);
        acc[7] = fmaf(a1.w, w, acc[7]);
    }
    {
        float4 t0, t1;
        t0.x = fmaxf(acc[0], 0.f); t0.y = fmaxf(acc[1], 0.f);
        t0.z = fmaxf(acc[2], 0.f); t0.w = fmaxf(acc[3], 0.f);
        t1.x = fmaxf(acc[4], 0.f); t1.y = fmaxf(acc[5], 0.f);
        t1.z = fmaxf(acc[6], 0.f); t1.w = fmaxf(acc[7], 0.f);
        float4* tp = reinterpret_cast<float4*>(&sT[f][eh * 8]);
        tp[0] = t0; tp[1] = t1;
    }
    __syncthreads();

    // GEMM2: m[i][f] = b2[f] + sum_k sT[k][i] * W2[k][f]
    float m[8];
    {
        const float bb = b2[f];
#pragma unroll
        for (int r = 0; r < 8; ++r) m[r] = bb;
    }
    for (int k = 0; k < HD; ++k) {
        const float w = W2[k * HD + f];
        const float4* tp = reinterpret_cast<const float4*>(&sT[k][eh * 8]);
        const float4 a0 = tp[0], a1 = tp[1];
        m[0] = fmaf(a0.x, w, m[0]);
        m[1] = fmaf(a0.y, w, m[1]);
        m[2] = fmaf(a0.z, w, m[2]);
        m[3] = fmaf(a0.w, w, m[3]);
        m[4] = fmaf(a1.x, w, m[4]);
        m[5] = fmaf(a1.y, w, m[5]);
        m[6] = fmaf(a1.z, w, m[6]);
        m[7] = fmaf(a1.w, w, m[7]);
    }
#pragma unroll
    for (int r = 0; r < 8; ++r) {
        const int i = eh * 8 + r;
        atomicAdd(&agg[(size_t)s_dst[i] * HD + f], m[r]);
    }
}

// ---------------- node update MLP + residual + LayerNorm ----------------
__global__ __launch_bounds__(256) void k_update(
    const float* __restrict__ h, const float* __restrict__ agg,
    const float* __restrict__ W1, const float* __restrict__ b1,  // [256][128]
    const float* __restrict__ W2, const float* __restrict__ b2,  // [128][128]
    const float* __restrict__ g, const float* __restrict__ bln,
    float* __restrict__ hout)
{
    __shared__ float sU[2 * NF][PADE]; // u_in transposed
    __shared__ float sT[HD][PADE];
    __shared__ float sX[TILE_N][NF + 4];
    __shared__ float sMu[TILE_N], sRs[TILE_N];

    const int tid = threadIdx.x;
    const int n0 = blockIdx.x * TILE_N;

    for (int idx = tid; idx < TILE_N * 2 * NF; idx += 256) {
        const int i = idx >> 8;
        const int k = idx & 255;
        const float v = (k < NF) ? h[(size_t)(n0 + i) * NF + k]
                                 : agg[(size_t)(n0 + i) * NF + (k - NF)];
        sU[k][i] = v;
    }
    __syncthreads();

    const int f = tid & (NF - 1);
    const int eh = tid >> 7;

    float acc[8];
    {
        const float bb = b1[f];
#pragma unroll
        for (int r = 0; r < 8; ++r) acc[r] = bb;
    }
    for (int k = 0; k < 2 * NF; ++k) {
        const float w = W1[k * HD + f];
        const float4* up = reinterpret_cast<const float4*>(&sU[k][eh * 8]);
        const float4 a0 = up[0], a1 = up[1];
        acc[0] = fmaf(a0.x, w, acc[0]);
        acc[1] = fmaf(a0.y, w, acc[1]);
        acc[2] = fmaf(a0.z, w, acc[2]);
        acc[3] = fmaf(a0.w, w, acc[3]);
        acc[4] = fmaf(a1.x, w, acc[4]);
        acc[5] = fmaf(a1.y, w, acc[5]);
        acc[6] = fmaf(a1.z, w, acc[6]);
        acc[7] = fmaf(a1.w, w, acc[7]);
    }
    {
        float4 t0, t1;
        t0.x = fmaxf(acc[0], 0.f); t0.y = fmaxf(acc[1], 0.f);
        t0.z = fmaxf(acc[2], 0.f); t0.w = fmaxf(acc[3], 0.f);
        t1.x = fmaxf(acc[4], 0.f); t1.y = fmaxf(acc[5], 0.f);
        t1.z = fmaxf(acc[6], 0.f); t1.w = fmaxf(acc[7], 0.f);
        float4* tp = reinterpret_cast<float4*>(&sT[f][eh * 8]);
        tp[0] = t0; tp[1] = t1;
    }
    __syncthreads();

    float d[8];
    {
        const float bb = b2[f];
#pragma unroll
        for (int r = 0; r < 8; ++r) d[r] = bb;
    }
    for (int k = 0; k < HD; ++k) {
        const float w = W2[k * NF + f];
        const float4* tp = reinterpret_cast<const float4*>(&sT[k][eh * 8]);
        const float4 a0 = tp[0], a1 = tp[1];
        d[0] = fmaf(a0.x, w, d[0]);
        d[1] = fmaf(a0.y, w, d[1]);
        d[2] = fmaf(a0.z, w, d[2]);
        d[3] = fmaf(a0.w, w, d[3]);
        d[4] = fmaf(a1.x, w, d[4]);
        d[5] = fmaf(a1.y, w, d[5]);
        d[6] = fmaf(a1.z, w, d[6]);
        d[7] = fmaf(a1.w, w, d[7]);
    }
#pragma unroll
    for (int r = 0; r < 8; ++r) {
        const int i = eh * 8 + r;
        const float x = h[(size_t)(n0 + i) * NF + f] + d[r];
        sX[i][f] = x;
    }
    __syncthreads();

    // LayerNorm stats: 16 lanes per node
    {
        const int i = tid >> 4, j = tid & 15;
        float s = 0.f, s2 = 0.f;
#pragma unroll
        for (int t = 0; t < 8; ++t) {
            const float x = sX[i][j + 16 * t];
            s += x; s2 = fmaf(x, x, s2);
        }
#pragma unroll
        for (int msk = 1; msk < 16; msk <<= 1) {
            s += __shfl_xor(s, msk, 64);
            s2 += __shfl_xor(s2, msk, 64);
        }
        if (j == 0) {
            const float mu = s * (1.f / NF);
            const float var = s2 * (1.f / NF) - mu * mu;
            sMu[i] = mu;
            sRs[i] = rsqrtf(var + 1e-5f);
        }
    }
    __syncthreads();

    const float gg = g[f], bb3 = bln[f];
#pragma unroll
    for (int r = 0; r < 8; ++r) {
        const int i = eh * 8 + r;
        hout[(size_t)(n0 + i) * NF + f] = (sX[i][f] - sMu[i]) * sRs[i] * gg + bb3;
    }
}

// ---------------- output projection ----------------
__global__ __launch_bounds__(256) void k_out(
    const float* __restrict__ h, const float* __restrict__ Wo,
    const float* __restrict__ bo, float* __restrict__ out)
{
    __shared__ float sH[NF][PADE];
    const int tid = threadIdx.x;
    const int n0 = blockIdx.x * TILE_N;
    for (int idx = tid; idx < TILE_N * NF; idx += 256) {
        const int i = idx >> 7;
        const int k = idx & 127;
        sH[k][i] = h[(size_t)(n0 + i) * NF + k];
    }
    __syncthreads();

    const int f = tid & (HD - 1);
    const int eh = tid >> 7;
    float acc[8];
    {
        const float bb = bo[f];
#pragma unroll
        for (int r = 0; r < 8; ++r) acc[r] = bb;
    }
    for (int k = 0; k < NF; ++k) {
        const float w = Wo[k * HD + f];
        const float4* hp = reinterpret_cast<const float4*>(&sH[k][eh * 8]);
        const float4 a0 = hp[0], a1 = hp[1];
        acc[0] = fmaf(a0.x, w, acc[0]);
        acc[1] = fmaf(a0.y, w, acc[1]);
        acc[2] = fmaf(a0.z, w, acc[2]);
        acc[3] = fmaf(a0.w, w, acc[3]);
        acc[4] = fmaf(a1.x, w, acc[4]);
        acc[5] = fmaf(a1.y, w, acc[5]);
        acc[6] = fmaf(a1.z, w, acc[6]);
        acc[7] = fmaf(a1.w, w, acc[7]);
    }
#pragma unroll
    for (int r = 0; r < 8; ++r) {
        out[(size_t)(n0 + eh * 8 + r) * HD + f] = acc[r];
    }
}

extern "C" void kernel_launch(void* const* d_in, const int* in_sizes, int n_in,
                              void* d_out, int out_size, void* d_ws, size_t ws_size,
                              hipStream_t stream)
{
    const float* coords = (const float*)d_in[0];
    const int* ei       = (const int*)d_in[1];
    const float* dist   = (const float*)d_in[2];
    const float* Wn  = (const float*)d_in[3];
    const float* bn  = (const float*)d_in[4];
    const float* We  = (const float*)d_in[5];
    const float* be  = (const float*)d_in[6];
    const float* mW1 = (const float*)d_in[7];
    const float* mb1 = (const float*)d_in[8];
    const float* mW2 = (const float*)d_in[9];
    const float* mb2 = (const float*)d_in[10];
    const float* uW1 = (const float*)d_in[11];
    const float* ub1 = (const float*)d_in[12];
    const float* uW2 = (const float*)d_in[13];
    const float* ub2 = (const float*)d_in[14];
    const float* lng = (const float*)d_in[15];
    const float* lnb = (const float*)d_in[16];
    const float* Wo  = (const float*)d_in[17];
    const float* bo  = (const float*)d_in[18];

    float* ws = (float*)d_ws;
    float* h0  = ws;
    float* h1  = ws + (size_t)NN * NF;
    float* agg = ws + 2 * (size_t)NN * NF;

    k_node_embed<<<NN, 128, 0, stream>>>(coords, Wn, bn, h0);

    float* hc = h0;
    float* hn = h1;
    for (int l = 0; l < NL; ++l) {
        hipMemsetAsync(agg, 0, (size_t)NN * NF * sizeof(float), stream);
        k_message<<<NE / TILE_E, 256, 0, stream>>>(
            hc, ei, dist, We, be,
            mW1 + (size_t)l * (2 * NF + EF) * HD, mb1 + l * HD,
            mW2 + (size_t)l * HD * HD, mb2 + l * HD, agg);
        k_update<<<NN / TILE_N, 256, 0, stream>>>(
            hc, agg,
            uW1 + (size_t)l * (NF + HD) * HD, ub1 + l * HD,
            uW2 + (size_t)l * HD * NF, ub2 + l * NF,
            lng + l * NF, lnb + l * NF, hn);
        float* t = hc; hc = hn; hn = t;
    }
    k_out<<<NN / TILE_N, 256, 0, stream>>>(hc, Wo, bo, (float*)d_out);
}

// Round 2
// 1186.550 us; speedup vs baseline: 3.6918x; 3.6918x over previous
//
#include <hip/hip_runtime.h>

#define NN 20000
#define NE 640000
#define NF 128
#define EF 32
#define HD 128
#define NL 3

typedef __bf16 bf16x8 __attribute__((ext_vector_type(8)));
typedef float f32x4 __attribute__((ext_vector_type(4)));

constexpr int BE = 64;         // edges per k_message block
constexpr int KA = 2 * NF + EF; // 288
constexpr int SAP = 296;       // sA padded row stride (bf16): 592B = 148 dw (conflict-free b128)
constexpr int STP = 136;       // sT padded row stride (bf16): 272B = 68 dw
constexpr int TILE_N = 16;
constexpr int PADE = 20;

// ---------------- weight repack: W[k][n] fp32 -> bf16 [(k>>3)][n][k&7] ----------------
__global__ __launch_bounds__(256) void k_prep(
    const float* __restrict__ mW1, const float* __restrict__ mW2,
    __bf16* __restrict__ W1f, __bf16* __restrict__ W2f)
{
    const int t = blockIdx.x * 256 + threadIdx.x;
    const int T1 = NL * KA * HD;
    for (int i = t; i < T1; i += gridDim.x * 256) {
        const int l = i / (KA * HD);
        const int r = i - l * (KA * HD);
        const int k = r / HD, n = r - (r / HD) * HD;
        W1f[(size_t)l * KA * HD + ((((k >> 3) * HD) + n) << 3) + (k & 7)] = (__bf16)mW1[i];
    }
    const int T2 = NL * HD * HD;
    for (int i = t; i < T2; i += gridDim.x * 256) {
        const int l = i / (HD * HD);
        const int r = i - l * (HD * HD);
        const int k = r / HD, n = r - (r / HD) * HD;
        W2f[(size_t)l * HD * HD + ((((k >> 3) * HD) + n) << 3) + (k & 7)] = (__bf16)mW2[i];
    }
}

// ---------------- edge embedding (hoisted, once): e = dist @ We + be -> bf16 ----------------
__global__ __launch_bounds__(256) void k_edge_embed(
    const float* __restrict__ dist, const float* __restrict__ We,
    const float* __restrict__ be, __bf16* __restrict__ ebf)
{
    __shared__ float sD[64][33];
    __shared__ float sW[32][33];
    const int tid = threadIdx.x;
    const int e0 = blockIdx.x * 64;
#pragma unroll
    for (int it = 0; it < 4; ++it) {
        const int idx = tid + it * 256;
        sW[idx >> 5][idx & 31] = We[idx];
    }
#pragma unroll
    for (int it = 0; it < 8; ++it) {
        const int idx = tid + it * 256;
        sD[idx >> 5][idx & 31] = dist[(size_t)e0 * EF + idx];
    }
    __syncthreads();
    const int i = tid >> 2;
    const int j0 = (tid & 3) * 8;
#pragma unroll
    for (int jj = 0; jj < 8; ++jj) {
        const int j = j0 + jj;
        float acc = be[j];
#pragma unroll
        for (int q = 0; q < EF; ++q) acc = fmaf(sD[i][q], sW[q][j], acc);
        ebf[(size_t)(e0 + i) * EF + j] = (__bf16)acc;
    }
}

// ---------------- node embedding ----------------
__global__ __launch_bounds__(128) void k_node_embed(
    const float* __restrict__ coords, const float* __restrict__ Wn,
    const float* __restrict__ bn, float* __restrict__ h, __bf16* __restrict__ hbf)
{
    const int node = blockIdx.x;
    const int f = threadIdx.x;
    __shared__ float c[8];
    if (f < 6) c[f] = coords[node * 6 + f];
    __syncthreads();
    float acc = bn[f];
#pragma unroll
    for (int k = 0; k < 6; ++k) acc = fmaf(c[k], Wn[k * NF + f], acc);
    h[(size_t)node * NF + f] = acc;
    hbf[(size_t)node * NF + f] = (__bf16)acc;
}

// ---------------- fused edge message (bf16 MFMA) + scatter-add ----------------
__global__ __launch_bounds__(256, 2) void k_message(
    const __bf16* __restrict__ hbf, const int* __restrict__ ei,
    const __bf16* __restrict__ ebf,
    const __bf16* __restrict__ W1f, const float* __restrict__ b1,
    const __bf16* __restrict__ W2f, const float* __restrict__ b2,
    float* __restrict__ agg)
{
    __shared__ __bf16 sA[BE][SAP];
    __shared__ __bf16 sT[BE][STP];
    __shared__ int s_src[BE], s_dst[BE];

    const int tid = threadIdx.x;
    const int e0 = blockIdx.x * BE;
    const int w = tid >> 6;
    const int lane = tid & 63;
    const int m16 = lane & 15;
    const int kb = lane >> 4;
    const int n0 = w * 32;

    if (tid < BE) s_src[tid] = ei[e0 + tid];
    else if (tid < 2 * BE) s_dst[tid - BE] = ei[NE + e0 + (tid - BE)];

    // B fragments for GEMM1, register-resident for the whole block
    bf16x8 bf1[9][2];
#pragma unroll
    for (int k9 = 0; k9 < 9; ++k9)
#pragma unroll
        for (int nf = 0; nf < 2; ++nf)
            bf1[k9][nf] = *reinterpret_cast<const bf16x8*>(
                W1f + ((((k9 * 4 + kb) * HD) + n0 + nf * 16 + m16) << 3));

    __syncthreads();

    // gather: sA[row] = [h[src] | h[dst] | e] (bf16, 16B chunks)
#pragma unroll
    for (int it = 0; it < 8; ++it) {
        const int c = tid + it * 256;
        const int row = c >> 5;
        const int part = (c >> 4) & 1;
        const int off = c & 15;
        const int idx = part ? s_dst[row] : s_src[row];
        const uint4 v = *reinterpret_cast<const uint4*>(hbf + (size_t)idx * NF + off * 8);
        *reinterpret_cast<uint4*>(&sA[row][part * NF + off * 8]) = v;
    }
    {
        const int row = tid >> 2;
        const int off = tid & 3;
        *reinterpret_cast<uint4*>(&sA[row][2 * NF + off * 8]) =
            *reinterpret_cast<const uint4*>(ebf + (size_t)(e0 + row) * EF + off * 8);
    }
    __syncthreads();

    // GEMM1: t = relu(sA @ W1 + b1); wave w owns cols [n0, n0+32)
    f32x4 acc1[4][2];
#pragma unroll
    for (int mt = 0; mt < 4; ++mt)
#pragma unroll
        for (int nf = 0; nf < 2; ++nf)
            acc1[mt][nf] = (f32x4){0.f, 0.f, 0.f, 0.f};

#pragma unroll
    for (int k9 = 0; k9 < 9; ++k9) {
#pragma unroll
        for (int mt = 0; mt < 4; ++mt) {
            const bf16x8 a = *reinterpret_cast<const bf16x8*>(&sA[mt * 16 + m16][k9 * 32 + kb * 8]);
            acc1[mt][0] = __builtin_amdgcn_mfma_f32_16x16x32_bf16(a, bf1[k9][0], acc1[mt][0], 0, 0, 0);
            acc1[mt][1] = __builtin_amdgcn_mfma_f32_16x16x32_bf16(a, bf1[k9][1], acc1[mt][1], 0, 0, 0);
        }
    }

    // B fragments for GEMM2 (issue loads before the barrier)
    bf16x8 bf2[4][2];
#pragma unroll
    for (int k4 = 0; k4 < 4; ++k4)
#pragma unroll
        for (int nf = 0; nf < 2; ++nf)
            bf2[k4][nf] = *reinterpret_cast<const bf16x8*>(
                W2f + ((((k4 * 4 + kb) * HD) + n0 + nf * 16 + m16) << 3));

    const float b1a = b1[n0 + m16];
    const float b1b = b1[n0 + 16 + m16];
#pragma unroll
    for (int mt = 0; mt < 4; ++mt) {
#pragma unroll
        for (int reg = 0; reg < 4; ++reg) {
            const int erow = mt * 16 + kb * 4 + reg;
            sT[erow][n0 + m16]      = (__bf16)fmaxf(acc1[mt][0][reg] + b1a, 0.f);
            sT[erow][n0 + 16 + m16] = (__bf16)fmaxf(acc1[mt][1][reg] + b1b, 0.f);
        }
    }
    __syncthreads();

    // GEMM2: m = t @ W2 + b2
    f32x4 acc2[4][2];
#pragma unroll
    for (int mt = 0; mt < 4; ++mt)
#pragma unroll
        for (int nf = 0; nf < 2; ++nf)
            acc2[mt][nf] = (f32x4){0.f, 0.f, 0.f, 0.f};

#pragma unroll
    for (int k4 = 0; k4 < 4; ++k4) {
#pragma unroll
        for (int mt = 0; mt < 4; ++mt) {
            const bf16x8 a = *reinterpret_cast<const bf16x8*>(&sT[mt * 16 + m16][k4 * 32 + kb * 8]);
            acc2[mt][0] = __builtin_amdgcn_mfma_f32_16x16x32_bf16(a, bf2[k4][0], acc2[mt][0], 0, 0, 0);
            acc2[mt][1] = __builtin_amdgcn_mfma_f32_16x16x32_bf16(a, bf2[k4][1], acc2[mt][1], 0, 0, 0);
        }
    }

    const float b2a = b2[n0 + m16];
    const float b2b = b2[n0 + 16 + m16];
#pragma unroll
    for (int mt = 0; mt < 4; ++mt) {
#pragma unroll
        for (int reg = 0; reg < 4; ++reg) {
            const int erow = mt * 16 + kb * 4 + reg;
            const int d = s_dst[erow];
            atomicAdd(&agg[(size_t)d * HD + n0 + m16], acc2[mt][0][reg] + b2a);
            atomicAdd(&agg[(size_t)d * HD + n0 + 16 + m16], acc2[mt][1][reg] + b2b);
        }
    }
}

// ---------------- node update MLP + residual + LayerNorm (fp32) ----------------
__global__ __launch_bounds__(256) void k_update(
    const float* __restrict__ h, const float* __restrict__ agg,
    const float* __restrict__ W1, const float* __restrict__ b1,
    const float* __restrict__ W2, const float* __restrict__ b2,
    const float* __restrict__ g, const float* __restrict__ bln,
    float* __restrict__ hout, __bf16* __restrict__ hbf_out)
{
    __shared__ float sU[2 * NF][PADE];
    __shared__ float sT2[HD][PADE];
    __shared__ float sX[TILE_N][NF + 4];
    __shared__ float sMu[TILE_N], sRs[TILE_N];

    const int tid = threadIdx.x;
    const int n0 = blockIdx.x * TILE_N;

    for (int idx = tid; idx < TILE_N * 2 * NF; idx += 256) {
        const int i = idx >> 8;
        const int k = idx & 255;
        const float v = (k < NF) ? h[(size_t)(n0 + i) * NF + k]
                                 : agg[(size_t)(n0 + i) * NF + (k - NF)];
        sU[k][i] = v;
    }
    __syncthreads();

    const int f = tid & (NF - 1);
    const int eh = tid >> 7;

    float acc[8];
    {
        const float bb = b1[f];
#pragma unroll
        for (int r = 0; r < 8; ++r) acc[r] = bb;
    }
    for (int k = 0; k < 2 * NF; ++k) {
        const float wv = W1[k * HD + f];
        const float4* up = reinterpret_cast<const float4*>(&sU[k][eh * 8]);
        const float4 a0 = up[0], a1 = up[1];
        acc[0] = fmaf(a0.x, wv, acc[0]);
        acc[1] = fmaf(a0.y, wv, acc[1]);
        acc[2] = fmaf(a0.z, wv, acc[2]);
        acc[3] = fmaf(a0.w, wv, acc[3]);
        acc[4] = fmaf(a1.x, wv, acc[4]);
        acc[5] = fmaf(a1.y, wv, acc[5]);
        acc[6] = fmaf(a1.z, wv, acc[6]);
        acc[7] = fmaf(a1.w, wv, acc[7]);
    }
    {
        float4 t0, t1;
        t0.x = fmaxf(acc[0], 0.f); t0.y = fmaxf(acc[1], 0.f);
        t0.z = fmaxf(acc[2], 0.f); t0.w = fmaxf(acc[3], 0.f);
        t1.x = fmaxf(acc[4], 0.f); t1.y = fmaxf(acc[5], 0.f);
        t1.z = fmaxf(acc[6], 0.f); t1.w = fmaxf(acc[7], 0.f);
        float4* tp = reinterpret_cast<float4*>(&sT2[f][eh * 8]);
        tp[0] = t0; tp[1] = t1;
    }
    __syncthreads();

    float d[8];
    {
        const float bb = b2[f];
#pragma unroll
        for (int r = 0; r < 8; ++r) d[r] = bb;
    }
    for (int k = 0; k < HD; ++k) {
        const float wv = W2[k * NF + f];
        const float4* tp = reinterpret_cast<const float4*>(&sT2[k][eh * 8]);
        const float4 a0 = tp[0], a1 = tp[1];
        d[0] = fmaf(a0.x, wv, d[0]);
        d[1] = fmaf(a0.y, wv, d[1]);
        d[2] = fmaf(a0.z, wv, d[2]);
        d[3] = fmaf(a0.w, wv, d[3]);
        d[4] = fmaf(a1.x, wv, d[4]);
        d[5] = fmaf(a1.y, wv, d[5]);
        d[6] = fmaf(a1.z, wv, d[6]);
        d[7] = fmaf(a1.w, wv, d[7]);
    }
#pragma unroll
    for (int r = 0; r < 8; ++r) {
        const int i = eh * 8 + r;
        sX[i][f] = h[(size_t)(n0 + i) * NF + f] + d[r];
    }
    __syncthreads();

    {
        const int i = tid >> 4, j = tid & 15;
        float s = 0.f, s2 = 0.f;
#pragma unroll
        for (int t = 0; t < 8; ++t) {
            const float x = sX[i][j + 16 * t];
            s += x; s2 = fmaf(x, x, s2);
        }
#pragma unroll
        for (int msk = 1; msk < 16; msk <<= 1) {
            s += __shfl_xor(s, msk, 64);
            s2 += __shfl_xor(s2, msk, 64);
        }
        if (j == 0) {
            const float mu = s * (1.f / NF);
            const float var = s2 * (1.f / NF) - mu * mu;
            sMu[i] = mu;
            sRs[i] = rsqrtf(var + 1e-5f);
        }
    }
    __syncthreads();

    const float gg = g[f], bb3 = bln[f];
#pragma unroll
    for (int r = 0; r < 8; ++r) {
        const int i = eh * 8 + r;
        const float v = (sX[i][f] - sMu[i]) * sRs[i] * gg + bb3;
        hout[(size_t)(n0 + i) * NF + f] = v;
        hbf_out[(size_t)(n0 + i) * NF + f] = (__bf16)v;
    }
}

// ---------------- output projection (fp32) ----------------
__global__ __launch_bounds__(256) void k_out(
    const float* __restrict__ h, const float* __restrict__ Wo,
    const float* __restrict__ bo, float* __restrict__ out)
{
    __shared__ float sH[NF][PADE];
    const int tid = threadIdx.x;
    const int n0 = blockIdx.x * TILE_N;
    for (int idx = tid; idx < TILE_N * NF; idx += 256) {
        const int i = idx >> 7;
        const int k = idx & 127;
        sH[k][i] = h[(size_t)(n0 + i) * NF + k];
    }
    __syncthreads();

    const int f = tid & (HD - 1);
    const int eh = tid >> 7;
    float acc[8];
    {
        const float bb = bo[f];
#pragma unroll
        for (int r = 0; r < 8; ++r) acc[r] = bb;
    }
    for (int k = 0; k < NF; ++k) {
        const float wv = Wo[k * HD + f];
        const float4* hp = reinterpret_cast<const float4*>(&sH[k][eh * 8]);
        const float4 a0 = hp[0], a1 = hp[1];
        acc[0] = fmaf(a0.x, wv, acc[0]);
        acc[1] = fmaf(a0.y, wv, acc[1]);
        acc[2] = fmaf(a0.z, wv, acc[2]);
        acc[3] = fmaf(a0.w, wv, acc[3]);
        acc[4] = fmaf(a1.x, wv, acc[4]);
        acc[5] = fmaf(a1.y, wv, acc[5]);
        acc[6] = fmaf(a1.z, wv, acc[6]);
        acc[7] = fmaf(a1.w, wv, acc[7]);
    }
#pragma unroll
    for (int r = 0; r < 8; ++r) {
        out[(size_t)(n0 + eh * 8 + r) * HD + f] = acc[r];
    }
}

extern "C" void kernel_launch(void* const* d_in, const int* in_sizes, int n_in,
                              void* d_out, int out_size, void* d_ws, size_t ws_size,
                              hipStream_t stream)
{
    const float* coords = (const float*)d_in[0];
    const int* ei       = (const int*)d_in[1];
    const float* dist   = (const float*)d_in[2];
    const float* Wn  = (const float*)d_in[3];
    const float* bn  = (const float*)d_in[4];
    const float* We  = (const float*)d_in[5];
    const float* be  = (const float*)d_in[6];
    const float* mW1 = (const float*)d_in[7];
    const float* mb1 = (const float*)d_in[8];
    const float* mW2 = (const float*)d_in[9];
    const float* mb2 = (const float*)d_in[10];
    const float* uW1 = (const float*)d_in[11];
    const float* ub1 = (const float*)d_in[12];
    const float* uW2 = (const float*)d_in[13];
    const float* ub2 = (const float*)d_in[14];
    const float* lng = (const float*)d_in[15];
    const float* lnb = (const float*)d_in[16];
    const float* Wo  = (const float*)d_in[17];
    const float* bo  = (const float*)d_in[18];

    char* p = (char*)d_ws;
    float* h0  = (float*)p; p += (size_t)NN * NF * 4;
    float* h1  = (float*)p; p += (size_t)NN * NF * 4;
    float* agg = (float*)p; p += (size_t)NN * NF * 4;
    __bf16* hbf = (__bf16*)p; p += (size_t)NN * NF * 2;
    __bf16* ebf = (__bf16*)p; p += (size_t)NE * EF * 2;
    __bf16* W1f = (__bf16*)p; p += (size_t)NL * KA * HD * 2;
    __bf16* W2f = (__bf16*)p; p += (size_t)NL * HD * HD * 2;

    k_prep<<<128, 256, 0, stream>>>(mW1, mW2, W1f, W2f);
    k_edge_embed<<<NE / 64, 256, 0, stream>>>(dist, We, be, ebf);
    k_node_embed<<<NN, 128, 0, stream>>>(coords, Wn, bn, h0, hbf);

    float* hc = h0;
    float* hn = h1;
    for (int l = 0; l < NL; ++l) {
        hipMemsetAsync(agg, 0, (size_t)NN * NF * sizeof(float), stream);
        k_message<<<NE / BE, 256, 0, stream>>>(
            hbf, ei, ebf,
            W1f + (size_t)l * KA * HD, mb1 + l * HD,
            W2f + (size_t)l * HD * HD, mb2 + l * HD, agg);
        k_update<<<NN / TILE_N, 256, 0, stream>>>(
            hc, agg,
            uW1 + (size_t)l * (NF + HD) * HD, ub1 + l * HD,
            uW2 + (size_t)l * HD * NF, ub2 + l * NF,
            lng + l * NF, lnb + l * NF, hn, hbf);
        float* t = hc; hc = hn; hn = t;
    }
    k_out<<<NN / TILE_N, 256, 0, stream>>>(hc, Wo, bo, (float*)d_out);
}

// Round 3
// 692.567 us; speedup vs baseline: 6.3249x; 1.7133x over previous
//
#include <hip/hip_runtime.h>

#define NN 20000
#define NE 640000
#define NF 128
#define EF 32
#define HD 128
#define NL 3

typedef __bf16 bf16x8 __attribute__((ext_vector_type(8)));
typedef float f32x4 __attribute__((ext_vector_type(4)));

constexpr int BE = 64;          // edges per k_message block
constexpr int KA = 2 * NF + EF; // 288
constexpr int SAP = 296;        // sA bf16 row stride
constexpr int STP = 136;        // sT bf16 row stride
constexpr int MP = 130;         // m_lds f32 row stride
constexpr int KU = NF + HD;     // 256
constexpr int SUP = 264;        // sU bf16 row stride (k_update)
constexpr int SXP = 132;        // sX f32 row stride

// ================= edge sort (counting sort by dst) =================
__global__ __launch_bounds__(256) void k_hist(const int* __restrict__ ei, int* __restrict__ cnt)
{
    const int e = blockIdx.x * 256 + threadIdx.x;
    if (e < NE) atomicAdd(&cnt[ei[NE + e]], 1);
}

__global__ __launch_bounds__(1024) void k_scan(const int* __restrict__ cnt, int* __restrict__ pos)
{
    __shared__ int ls[1024];
    const int tid = threadIdx.x;
    const int C = 20; // 1024*20 >= 20000
    const int base = tid * C;
    int s = 0;
#pragma unroll
    for (int i = 0; i < C; ++i) {
        const int idx = base + i;
        if (idx < NN) s += cnt[idx];
    }
    ls[tid] = s;
    __syncthreads();
    for (int off = 1; off < 1024; off <<= 1) {
        const int v = (tid >= off) ? ls[tid - off] : 0;
        __syncthreads();
        ls[tid] += v;
        __syncthreads();
    }
    int p = tid ? ls[tid - 1] : 0;
#pragma unroll
    for (int i = 0; i < C; ++i) {
        const int idx = base + i;
        if (idx < NN) { pos[idx] = p; p += cnt[idx]; }
    }
}

__global__ __launch_bounds__(256) void k_scatter(
    const int* __restrict__ ei, int* __restrict__ pos,
    int* __restrict__ srcS, int* __restrict__ dstS, int* __restrict__ invp)
{
    const int e = blockIdx.x * 256 + threadIdx.x;
    if (e < NE) {
        const int d = ei[NE + e];
        const int p = atomicAdd(&pos[d], 1);
        srcS[p] = ei[e];
        dstS[p] = d;
        invp[e] = p;
    }
}

// ================= weight repack: W[k][n] fp32 -> bf16 [(k>>3)][n][k&7] =================
__device__ __forceinline__ void repack(const float* src, __bf16* dst, int total, int t, int stride)
{
    for (int i = t; i < total; i += stride) {
        const int kn = i & (16384 - 1); // per-slab when K*N multiple of 16384? not general; unused
        (void)kn;
    }
}

__global__ __launch_bounds__(256) void k_prep(
    const float* __restrict__ mW1, const float* __restrict__ mW2,
    const float* __restrict__ uW1, const float* __restrict__ uW2,
    const float* __restrict__ Wo,
    __bf16* __restrict__ W1f, __bf16* __restrict__ W2f,
    __bf16* __restrict__ U1f, __bf16* __restrict__ U2f,
    __bf16* __restrict__ Wof)
{
    const int t = blockIdx.x * 256 + threadIdx.x;
    const int stride = gridDim.x * 256;
    // W1: NL x KA x 128
    for (int i = t; i < NL * KA * HD; i += stride) {
        const int l = i / (KA * HD);
        const int r = i - l * (KA * HD);
        const int k = r >> 7, n = r & 127;
        W1f[(size_t)l * KA * HD + ((((k >> 3) * HD) + n) << 3) + (k & 7)] = (__bf16)mW1[i];
    }
    // W2: NL x 128 x 128
    for (int i = t; i < NL * HD * HD; i += stride) {
        const int l = i / (HD * HD);
        const int r = i - l * (HD * HD);
        const int k = r >> 7, n = r & 127;
        W2f[(size_t)l * HD * HD + ((((k >> 3) * HD) + n) << 3) + (k & 7)] = (__bf16)mW2[i];
    }
    // U1: NL x 256 x 128
    for (int i = t; i < NL * KU * HD; i += stride) {
        const int l = i / (KU * HD);
        const int r = i - l * (KU * HD);
        const int k = r >> 7, n = r & 127;
        U1f[(size_t)l * KU * HD + ((((k >> 3) * HD) + n) << 3) + (k & 7)] = (__bf16)uW1[i];
    }
    // U2: NL x 128 x 128
    for (int i = t; i < NL * HD * NF; i += stride) {
        const int l = i / (HD * NF);
        const int r = i - l * (HD * NF);
        const int k = r >> 7, n = r & 127;
        U2f[(size_t)l * HD * NF + ((((k >> 3) * NF) + n) << 3) + (k & 7)] = (__bf16)uW2[i];
    }
    // Wo: 128 x 128
    for (int i = t; i < NF * HD; i += stride) {
        const int k = i >> 7, n = i & 127;
        Wof[((((k >> 3) * HD) + n) << 3) + (k & 7)] = (__bf16)Wo[i];
    }
}

// ================= edge embedding -> sorted bf16 rows =================
__global__ __launch_bounds__(256) void k_edge_embed(
    const float* __restrict__ dist, const float* __restrict__ We,
    const float* __restrict__ be, const int* __restrict__ invp,
    __bf16* __restrict__ ebfS)
{
    __shared__ float sD[64][33];
    __shared__ float sW[32][33];
    const int tid = threadIdx.x;
    const int e0 = blockIdx.x * 64;
#pragma unroll
    for (int it = 0; it < 4; ++it) {
        const int idx = tid + it * 256;
        sW[idx >> 5][idx & 31] = We[idx];
    }
#pragma unroll
    for (int it = 0; it < 8; ++it) {
        const int idx = tid + it * 256;
        sD[idx >> 5][idx & 31] = dist[(size_t)e0 * EF + idx];
    }
    __syncthreads();
    const int i = tid >> 2;
    const int j0 = (tid & 3) * 8;
    __bf16 vals[8];
#pragma unroll
    for (int jj = 0; jj < 8; ++jj) {
        const int j = j0 + jj;
        float acc = be[j];
#pragma unroll
        for (int q = 0; q < EF; ++q) acc = fmaf(sD[i][q], sW[q][j], acc);
        vals[jj] = (__bf16)acc;
    }
    const int p = invp[e0 + i];
    *reinterpret_cast<uint4*>(ebfS + (size_t)p * EF + j0) = *reinterpret_cast<const uint4*>(vals);
}

// ================= node embedding =================
__global__ __launch_bounds__(128) void k_node_embed(
    const float* __restrict__ coords, const float* __restrict__ Wn,
    const float* __restrict__ bn, float* __restrict__ h, __bf16* __restrict__ hbf)
{
    const int node = blockIdx.x;
    const int f = threadIdx.x;
    __shared__ float c[8];
    if (f < 6) c[f] = coords[node * 6 + f];
    __syncthreads();
    float acc = bn[f];
#pragma unroll
    for (int k = 0; k < 6; ++k) acc = fmaf(c[k], Wn[k * NF + f], acc);
    h[(size_t)node * NF + f] = acc;
    hbf[(size_t)node * NF + f] = (__bf16)acc;
}

// ================= fused edge message (bf16 MFMA) + segmented scatter =================
__global__ __launch_bounds__(256, 4) void k_message(
    const __bf16* __restrict__ hbf,
    const int* __restrict__ srcS, const int* __restrict__ dstS,
    const __bf16* __restrict__ ebfS,
    const __bf16* __restrict__ W1f, const float* __restrict__ b1,
    const __bf16* __restrict__ W2f, const float* __restrict__ b2,
    float* __restrict__ agg)
{
    __shared__ __attribute__((aligned(16))) __bf16 R[BE * SAP]; // sA -> sT -> sM overlay
    __shared__ int s_src[BE], s_dst[BE];
    __bf16* sA = R;
    __bf16* sT = R;
    float* sM = (float*)R;

    const int tid = threadIdx.x;
    const int e0 = blockIdx.x * BE;
    const int w = tid >> 6;
    const int lane = tid & 63;
    const int m16 = lane & 15;
    const int kb = lane >> 4;
    const int n0 = w * 32;

    if (tid < BE) {
        s_src[tid] = srcS[e0 + tid];
        s_dst[tid] = dstS[e0 + tid];
    }

    // register-resident B fragments for GEMM1
    bf16x8 bf1[9][2];
#pragma unroll
    for (int k9 = 0; k9 < 9; ++k9)
#pragma unroll
        for (int nf = 0; nf < 2; ++nf)
            bf1[k9][nf] = *reinterpret_cast<const bf16x8*>(
                W1f + ((((k9 * 4 + kb) * HD) + n0 + nf * 16 + m16) << 3));

    __syncthreads(); // s_src/s_dst visible

    // gather: sA[row] = [h[src] | h[dst] | e]
#pragma unroll
    for (int it = 0; it < 8; ++it) {
        const int c = tid + it * 256;
        const int row = c >> 5;
        const int part = (c >> 4) & 1;
        const int off = c & 15;
        const int idx = part ? s_dst[row] : s_src[row];
        *reinterpret_cast<uint4*>(&sA[row * SAP + part * NF + off * 8]) =
            *reinterpret_cast<const uint4*>(hbf + (size_t)idx * NF + off * 8);
    }
    {
        const int row = tid >> 2;
        const int off = tid & 3;
        *reinterpret_cast<uint4*>(&sA[row * SAP + 2 * NF + off * 8]) =
            *reinterpret_cast<const uint4*>(ebfS + (size_t)(e0 + row) * EF + off * 8);
    }
    __syncthreads();

    // GEMM1
    f32x4 acc1[4][2];
#pragma unroll
    for (int mt = 0; mt < 4; ++mt)
#pragma unroll
        for (int nf = 0; nf < 2; ++nf) acc1[mt][nf] = (f32x4){0.f, 0.f, 0.f, 0.f};
#pragma unroll
    for (int k9 = 0; k9 < 9; ++k9) {
#pragma unroll
        for (int mt = 0; mt < 4; ++mt) {
            const bf16x8 a = *reinterpret_cast<const bf16x8*>(&sA[(mt * 16 + m16) * SAP + k9 * 32 + kb * 8]);
            acc1[mt][0] = __builtin_amdgcn_mfma_f32_16x16x32_bf16(a, bf1[k9][0], acc1[mt][0], 0, 0, 0);
            acc1[mt][1] = __builtin_amdgcn_mfma_f32_16x16x32_bf16(a, bf1[k9][1], acc1[mt][1], 0, 0, 0);
        }
    }

    // B fragments for GEMM2
    bf16x8 bf2[4][2];
#pragma unroll
    for (int k4 = 0; k4 < 4; ++k4)
#pragma unroll
        for (int nf = 0; nf < 2; ++nf)
            bf2[k4][nf] = *reinterpret_cast<const bf16x8*>(
                W2f + ((((k4 * 4 + kb) * HD) + n0 + nf * 16 + m16) << 3));

    __syncthreads(); // all sA reads done

    {
        const float b1a = b1[n0 + m16];
        const float b1b = b1[n0 + 16 + m16];
#pragma unroll
        for (int mt = 0; mt < 4; ++mt) {
#pragma unroll
            for (int reg = 0; reg < 4; ++reg) {
                const int erow = mt * 16 + kb * 4 + reg;
                sT[erow * STP + n0 + m16] = (__bf16)fmaxf(acc1[mt][0][reg] + b1a, 0.f);
                sT[erow * STP + n0 + 16 + m16] = (__bf16)fmaxf(acc1[mt][1][reg] + b1b, 0.f);
            }
        }
    }
    __syncthreads();

    // GEMM2
    f32x4 acc2[4][2];
#pragma unroll
    for (int mt = 0; mt < 4; ++mt)
#pragma unroll
        for (int nf = 0; nf < 2; ++nf) acc2[mt][nf] = (f32x4){0.f, 0.f, 0.f, 0.f};
#pragma unroll
    for (int k4 = 0; k4 < 4; ++k4) {
#pragma unroll
        for (int mt = 0; mt < 4; ++mt) {
            const bf16x8 a = *reinterpret_cast<const bf16x8*>(&sT[(mt * 16 + m16) * STP + k4 * 32 + kb * 8]);
            acc2[mt][0] = __builtin_amdgcn_mfma_f32_16x16x32_bf16(a, bf2[k4][0], acc2[mt][0], 0, 0, 0);
            acc2[mt][1] = __builtin_amdgcn_mfma_f32_16x16x32_bf16(a, bf2[k4][1], acc2[mt][1], 0, 0, 0);
        }
    }
    __syncthreads(); // all sT reads done

    {
        const float b2a = b2[n0 + m16];
        const float b2b = b2[n0 + 16 + m16];
#pragma unroll
        for (int mt = 0; mt < 4; ++mt) {
#pragma unroll
            for (int reg = 0; reg < 4; ++reg) {
                const int erow = mt * 16 + kb * 4 + reg;
                sM[erow * MP + n0 + m16] = acc2[mt][0][reg] + b2a;
                sM[erow * MP + n0 + 16 + m16] = acc2[mt][1][reg] + b2b;
            }
        }
    }
    __syncthreads();

    // segmented reduction over dst-sorted rows -> few atomics
    {
        const int col = tid & 127;
        const int r0 = (tid >> 7) * 32;
        int cur = s_dst[r0];
        float s = sM[r0 * MP + col];
#pragma unroll
        for (int r = r0 + 1; r < r0 + 32; ++r) {
            const int d2 = s_dst[r];
            const float v = sM[r * MP + col];
            if (d2 != cur) {
                atomicAdd(&agg[(size_t)cur * HD + col], s);
                cur = d2;
                s = v;
            } else {
                s += v;
            }
        }
        atomicAdd(&agg[(size_t)cur * HD + col], s);
    }
}

// ================= node update MLP (bf16 MFMA) + residual + LayerNorm, in-place =================
__global__ __launch_bounds__(256, 4) void k_update(
    float* __restrict__ h, const float* __restrict__ agg,
    const __bf16* __restrict__ U1f, const float* __restrict__ b1,
    const __bf16* __restrict__ U2f, const float* __restrict__ b2,
    const float* __restrict__ g, const float* __restrict__ bln,
    __bf16* __restrict__ hbf)
{
    __shared__ __attribute__((aligned(16))) __bf16 R[64 * SUP]; // sU -> sT -> sX overlay
    __bf16* sU = R;
    __bf16* sT = R;
    float* sX = (float*)R;

    const int tid = threadIdx.x;
    const int n0 = blockIdx.x * 64;
    const int w = tid >> 6;
    const int lane = tid & 63;
    const int m16 = lane & 15;
    const int kb = lane >> 4;
    const int nw0 = w * 32;

    // gather u_in = [hbf | agg->bf16]
#pragma unroll
    for (int it = 0; it < 4; ++it) {
        const int c = tid + it * 256;
        const int row = c >> 4;
        const int off = c & 15;
        const int node = min(n0 + row, NN - 1);
        *reinterpret_cast<uint4*>(&sU[row * SUP + off * 8]) =
            *reinterpret_cast<const uint4*>(hbf + (size_t)node * NF + off * 8);
    }
#pragma unroll
    for (int it = 0; it < 8; ++it) {
        const int c = tid + it * 256;
        const int row = c >> 5;
        const int off = c & 31;
        const int node = min(n0 + row, NN - 1);
        const float4 v = *reinterpret_cast<const float4*>(agg + (size_t)node * HD + off * 4);
        union { __bf16 b[4]; uint2 u; } cv;
        cv.b[0] = (__bf16)v.x; cv.b[1] = (__bf16)v.y; cv.b[2] = (__bf16)v.z; cv.b[3] = (__bf16)v.w;
        *reinterpret_cast<uint2*>(&sU[row * SUP + NF + off * 4]) = cv.u;
    }
    __syncthreads();

    // GEMM1 (K=256)
    f32x4 acc1[4][2];
#pragma unroll
    for (int mt = 0; mt < 4; ++mt)
#pragma unroll
        for (int nf = 0; nf < 2; ++nf) acc1[mt][nf] = (f32x4){0.f, 0.f, 0.f, 0.f};
#pragma unroll
    for (int k8 = 0; k8 < 8; ++k8) {
        bf16x8 bA = *reinterpret_cast<const bf16x8*>(U1f + ((((k8 * 4 + kb) * HD) + nw0 + m16) << 3));
        bf16x8 bB = *reinterpret_cast<const bf16x8*>(U1f + ((((k8 * 4 + kb) * HD) + nw0 + 16 + m16) << 3));
#pragma unroll
        for (int mt = 0; mt < 4; ++mt) {
            const bf16x8 a = *reinterpret_cast<const bf16x8*>(&sU[(mt * 16 + m16) * SUP + k8 * 32 + kb * 8]);
            acc1[mt][0] = __builtin_amdgcn_mfma_f32_16x16x32_bf16(a, bA, acc1[mt][0], 0, 0, 0);
            acc1[mt][1] = __builtin_amdgcn_mfma_f32_16x16x32_bf16(a, bB, acc1[mt][1], 0, 0, 0);
        }
    }
    __syncthreads(); // all sU reads done

    {
        const float b1a = b1[nw0 + m16];
        const float b1b = b1[nw0 + 16 + m16];
#pragma unroll
        for (int mt = 0; mt < 4; ++mt) {
#pragma unroll
            for (int reg = 0; reg < 4; ++reg) {
                const int erow = mt * 16 + kb * 4 + reg;
                sT[erow * STP + nw0 + m16] = (__bf16)fmaxf(acc1[mt][0][reg] + b1a, 0.f);
                sT[erow * STP + nw0 + 16 + m16] = (__bf16)fmaxf(acc1[mt][1][reg] + b1b, 0.f);
            }
        }
    }
    __syncthreads();

    // GEMM2 (K=128)
    f32x4 acc2[4][2];
#pragma unroll
    for (int mt = 0; mt < 4; ++mt)
#pragma unroll
        for (int nf = 0; nf < 2; ++nf) acc2[mt][nf] = (f32x4){0.f, 0.f, 0.f, 0.f};
#pragma unroll
    for (int k4 = 0; k4 < 4; ++k4) {
        bf16x8 bA = *reinterpret_cast<const bf16x8*>(U2f + ((((k4 * 4 + kb) * NF) + nw0 + m16) << 3));
        bf16x8 bB = *reinterpret_cast<const bf16x8*>(U2f + ((((k4 * 4 + kb) * NF) + nw0 + 16 + m16) << 3));
#pragma unroll
        for (int mt = 0; mt < 4; ++mt) {
            const bf16x8 a = *reinterpret_cast<const bf16x8*>(&sT[(mt * 16 + m16) * STP + k4 * 32 + kb * 8]);
            acc2[mt][0] = __builtin_amdgcn_mfma_f32_16x16x32_bf16(a, bA, acc2[mt][0], 0, 0, 0);
            acc2[mt][1] = __builtin_amdgcn_mfma_f32_16x16x32_bf16(a, bB, acc2[mt][1], 0, 0, 0);
        }
    }
    __syncthreads(); // all sT reads done

    // residual: x = h + delta -> sX
    {
        const float b2a = b2[nw0 + m16];
        const float b2b = b2[nw0 + 16 + m16];
#pragma unroll
        for (int mt = 0; mt < 4; ++mt) {
#pragma unroll
            for (int reg = 0; reg < 4; ++reg) {
                const int erow = mt * 16 + kb * 4 + reg;
                const int node = min(n0 + erow, NN - 1);
                const float h0 = h[(size_t)node * NF + nw0 + m16];
                const float h1 = h[(size_t)node * NF + nw0 + 16 + m16];
                sX[erow * SXP + nw0 + m16] = h0 + acc2[mt][0][reg] + b2a;
                sX[erow * SXP + nw0 + 16 + m16] = h1 + acc2[mt][1][reg] + b2b;
            }
        }
    }
    __syncthreads();

    // LayerNorm: 4 lanes per node
    {
        const int i = tid >> 2;
        const int j = tid & 3;
        float s = 0.f, s2 = 0.f;
#pragma unroll
        for (int t = 0; t < 32; ++t) {
            const float x = sX[i * SXP + j + 4 * t];
            s += x;
            s2 = fmaf(x, x, s2);
        }
        s += __shfl_xor(s, 1, 64);
        s2 += __shfl_xor(s2, 1, 64);
        s += __shfl_xor(s, 2, 64);
        s2 += __shfl_xor(s2, 2, 64);
        const float mu = s * (1.f / NF);
        const float var = s2 * (1.f / NF) - mu * mu;
        const float rs = rsqrtf(var + 1e-5f);
        const int node = n0 + i;
        if (node < NN) {
#pragma unroll
            for (int t = 0; t < 32; ++t) {
                const int col = j + 4 * t;
                const float v = (sX[i * SXP + col] - mu) * rs * g[col] + bln[col];
                h[(size_t)node * NF + col] = v;
                hbf[(size_t)node * NF + col] = (__bf16)v;
            }
        }
    }
}

// ================= output projection (bf16 MFMA) =================
__global__ __launch_bounds__(256, 4) void k_out(
    const __bf16* __restrict__ hbf, const __bf16* __restrict__ Wof,
    const float* __restrict__ bo, float* __restrict__ out)
{
    __shared__ __attribute__((aligned(16))) __bf16 sH[64 * STP];
    const int tid = threadIdx.x;
    const int n0 = blockIdx.x * 64;
    const int w = tid >> 6;
    const int lane = tid & 63;
    const int m16 = lane & 15;
    const int kb = lane >> 4;
    const int nw0 = w * 32;

#pragma unroll
    for (int it = 0; it < 4; ++it) {
        const int c = tid + it * 256;
        const int row = c >> 4;
        const int off = c & 15;
        const int node = min(n0 + row, NN - 1);
        *reinterpret_cast<uint4*>(&sH[row * STP + off * 8]) =
            *reinterpret_cast<const uint4*>(hbf + (size_t)node * NF + off * 8);
    }
    __syncthreads();

    f32x4 acc[4][2];
#pragma unroll
    for (int mt = 0; mt < 4; ++mt)
#pragma unroll
        for (int nf = 0; nf < 2; ++nf) acc[mt][nf] = (f32x4){0.f, 0.f, 0.f, 0.f};
#pragma unroll
    for (int k4 = 0; k4 < 4; ++k4) {
        bf16x8 bA = *reinterpret_cast<const bf16x8*>(Wof + ((((k4 * 4 + kb) * HD) + nw0 + m16) << 3));
        bf16x8 bB = *reinterpret_cast<const bf16x8*>(Wof + ((((k4 * 4 + kb) * HD) + nw0 + 16 + m16) << 3));
#pragma unroll
        for (int mt = 0; mt < 4; ++mt) {
            const bf16x8 a = *reinterpret_cast<const bf16x8*>(&sH[(mt * 16 + m16) * STP + k4 * 32 + kb * 8]);
            acc[mt][0] = __builtin_amdgcn_mfma_f32_16x16x32_bf16(a, bA, acc[mt][0], 0, 0, 0);
            acc[mt][1] = __builtin_amdgcn_mfma_f32_16x16x32_bf16(a, bB, acc[mt][1], 0, 0, 0);
        }
    }
    const float boa = bo[nw0 + m16];
    const float bob = bo[nw0 + 16 + m16];
#pragma unroll
    for (int mt = 0; mt < 4; ++mt) {
#pragma unroll
        for (int reg = 0; reg < 4; ++reg) {
            const int erow = mt * 16 + kb * 4 + reg;
            const int node = n0 + erow;
            if (node < NN) {
                out[(size_t)node * HD + nw0 + m16] = acc[mt][0][reg] + boa;
                out[(size_t)node * HD + nw0 + 16 + m16] = acc[mt][1][reg] + bob;
            }
        }
    }
}

extern "C" void kernel_launch(void* const* d_in, const int* in_sizes, int n_in,
                              void* d_out, int out_size, void* d_ws, size_t ws_size,
                              hipStream_t stream)
{
    const float* coords = (const float*)d_in[0];
    const int* ei       = (const int*)d_in[1];
    const float* dist   = (const float*)d_in[2];
    const float* Wn  = (const float*)d_in[3];
    const float* bn  = (const float*)d_in[4];
    const float* We  = (const float*)d_in[5];
    const float* be  = (const float*)d_in[6];
    const float* mW1 = (const float*)d_in[7];
    const float* mb1 = (const float*)d_in[8];
    const float* mW2 = (const float*)d_in[9];
    const float* mb2 = (const float*)d_in[10];
    const float* uW1 = (const float*)d_in[11];
    const float* ub1 = (const float*)d_in[12];
    const float* uW2 = (const float*)d_in[13];
    const float* ub2 = (const float*)d_in[14];
    const float* lng = (const float*)d_in[15];
    const float* lnb = (const float*)d_in[16];
    const float* Wo  = (const float*)d_in[17];
    const float* bo  = (const float*)d_in[18];

    char* p = (char*)d_ws;
    float* h   = (float*)p; p += (size_t)NN * NF * 4;
    float* agg = (float*)p; p += (size_t)NN * NF * 4;
    __bf16* hbf  = (__bf16*)p; p += (size_t)NN * NF * 2;
    __bf16* ebfS = (__bf16*)p; p += (size_t)NE * EF * 2;
    __bf16* W1f = (__bf16*)p; p += (size_t)NL * KA * HD * 2;
    __bf16* W2f = (__bf16*)p; p += (size_t)NL * HD * HD * 2;
    __bf16* U1f = (__bf16*)p; p += (size_t)NL * KU * HD * 2;
    __bf16* U2f = (__bf16*)p; p += (size_t)NL * HD * NF * 2;
    __bf16* Wof = (__bf16*)p; p += (size_t)NF * HD * 2;
    int* cnt  = (int*)p; p += (size_t)NN * 4;
    int* pos  = (int*)p; p += (size_t)NN * 4;
    int* srcS = (int*)p; p += (size_t)NE * 4;
    int* dstS = (int*)p; p += (size_t)NE * 4;
    int* invp = (int*)p; p += (size_t)NE * 4;

    // edge sort by dst (counting sort)
    hipMemsetAsync(cnt, 0, (size_t)NN * 4, stream);
    k_hist<<<(NE + 255) / 256, 256, 0, stream>>>(ei, cnt);
    k_scan<<<1, 1024, 0, stream>>>(cnt, pos);
    k_scatter<<<(NE + 255) / 256, 256, 0, stream>>>(ei, pos, srcS, dstS, invp);

    k_prep<<<256, 256, 0, stream>>>(mW1, mW2, uW1, uW2, Wo, W1f, W2f, U1f, U2f, Wof);
    k_node_embed<<<NN, 128, 0, stream>>>(coords, Wn, bn, h, hbf);
    k_edge_embed<<<NE / 64, 256, 0, stream>>>(dist, We, be, invp, ebfS);

    const int nbU = (NN + 63) / 64;
    for (int l = 0; l < NL; ++l) {
        hipMemsetAsync(agg, 0, (size_t)NN * NF * sizeof(float), stream);
        k_message<<<NE / BE, 256, 0, stream>>>(
            hbf, srcS, dstS, ebfS,
            W1f + (size_t)l * KA * HD, mb1 + l * HD,
            W2f + (size_t)l * HD * HD, mb2 + l * HD, agg);
        k_update<<<nbU, 256, 0, stream>>>(
            h, agg,
            U1f + (size_t)l * KU * HD, ub1 + l * HD,
            U2f + (size_t)l * HD * NF, ub2 + l * NF,
            lng + l * NF, lnb + l * NF, hbf);
    }
    k_out<<<nbU, 256, 0, stream>>>(hbf, Wof, bo, (float*)d_out);
}